// Round 2
// baseline (226.322 us; speedup 1.0000x reference)
//
#include <hip/hip_runtime.h>

#define B_SZ 256
#define P_SZ 128
#define F_SZ 7
#define H_SZ 256
#define KNB  16
#define CH_OUT 264   // H + F + 1

typedef __bf16 bf16x8 __attribute__((ext_vector_type(8)));
typedef __bf16 bf16x4 __attribute__((ext_vector_type(4)));
typedef float  f32x4  __attribute__((ext_vector_type(4)));

// ---------------------------------------------------------------------------
// Grid = 512: block (b, ph) handles batch b, points ph*64..+63. 8 waves.
// THIS ROUND: launch_bounds(512,2) -> 256-reg cap, 1 block/CU. The 128-reg cap
// was forcing (a) ~40 MB of scratch spill traffic (round-1 counters: FETCH
// 11->26 MB, WRITE 55->81 MB) and (b) a narrow N=32 per-wave W2 split, which
// made every wave re-read the FULL 32 KB h1 tile from LDS (8x redundancy,
// ~57 us of LDS-pipe time = the dominant term). Now each wave owns N=64 cols
// (w2f[4][8] = 128 regs, AGPR-friendly read-only) and 2 of the 4 points, so
// phase-2 LDS reads halve (16 b128/wave/iter) and nothing spills.
// CRITICAL: every loop that indexes the KNN register array arr[] must be
// FULLY UNROLLED (constant indices) or the compiler demotes arr to scratch.
//  KNN: unchanged (f64 exact keys, quarter scan + 2 merges).
//  Main loop software-pipelined: sH1 double-buffered (2 x 32 KB), ONE barrier
//    per iteration: phase1(it+1)->buf[!cur] overlaps phase2(it)<-buf[cur].
//  sW1 compressed to [16][32][8] (8 KB): rows 32..63 were structural zeros
//    (K padded 16->32). Lanes >=32 read sW1[tt][lane&31] -- same-address
//    broadcast (free); their A-frag garbage multiplies af's structural zeros
//    at k>=16, so the MFMA result is bit-identical.
//  sH1 chunk-major [pt][kc=k/8][m=16][8el]: phase-2 b128 reads conflict-free,
//  phase-1 b64 stores 2-way (free).
// ---------------------------------------------------------------------------
__global__ __launch_bounds__(512, 2) void edgeconv_fused(
    const float* __restrict__ ev, const float* __restrict__ W1,
    const float* __restrict__ b1, const float* __restrict__ W2,
    const float* __restrict__ b2, float* __restrict__ out) {
  const int b    = blockIdx.x >> 1;
  const int ph   = blockIdx.x & 1;
  const int tid  = threadIdx.x;
  const int lane = tid & 63;
  const int wave = tid >> 6;         // 0..7
  const int qd   = lane >> 4;        // 0..3
  const int c16  = lane & 15;

  __shared__ float sFeats[P_SZ][8];                     // 4 KB (full batch)
  __shared__ __align__(16) __bf16 sW1[16][32][8];       // 8 KB, k<16 half only
  __shared__ unsigned short sIdx[64][KNB];              // 2 KB (this block's pts)
  // union: 2 x sH1 double buffer (2 x 32768 B); KNN lists 4*17*64*8 = 34816 B
  // overlay the front (disjoint lifetimes, barrier-separated).
  __shared__ __align__(16) unsigned char sU[2 * 32768];
  double* lists = (double*)sU;                          // [quarter][17][64]
  __bf16* buf0  = (__bf16*)sU;                          // sH1 buffer 0
  __bf16* buf1  = (__bf16*)(sU + 32768);                // sH1 buffer 1

  // ---- stage events + W1 frags (bias folded in at k=14; k<16 half only) ----
  if (tid < 2 * P_SZ)
    ((float4*)&sFeats[0][0])[tid] = ((const float4*)(ev + (size_t)b * P_SZ * 8))[tid];
  if (tid < 512) {   // 16 tiles x 32 rows
    const int t = tid >> 5, l32 = tid & 31;
    const int qq = l32 >> 4, cc = l32 & 15;
    const int n = t * 16 + cc;
    bf16x8 v;
#pragma unroll
    for (int j = 0; j < 8; ++j) {
      const int k = qq * 8 + j;
      float w = 0.0f;
      if (k < 2 * F_SZ) w = W1[k * H_SZ + n];
      else if (k == 2 * F_SZ) w = b1[n];   // bias row, edge supplies 1.0
      v[j] = (__bf16)w;
    }
    *(bf16x8*)&sW1[t][l32][0] = v;
  }
  __syncthreads();

  // ---- feats passthrough + mask channel (needs only sFeats) ----
  {
    const int pl = tid >> 3, ch = tid & 7;       // 64 pts x 8 ch
    const int pg = ph * 64 + pl;
    const float msk = sFeats[pg][7];
    float v;
    if (ch < 7) {
      float fv = sFeats[pg][ch];
      fv = fv > 0.0f ? fv : 0.2f * fv;
      v = (msk > 0.5f ? 1.0f : 0.0f) * fv;
    } else {
      v = msk;
    }
    out[((size_t)(b * P_SZ + pg)) * CH_OUT + H_SZ + ch] = v;
  }

  // =====================  KNN (f64 min/max network)  =====================
  // lane-point = ph*64 + lane; quarter q = wave&3 scans cands q*32..+31.
  const int q  = wave & 3;
  const int ip = ph * 64 + lane;
  const float xi = sFeats[ip][0], yi = sFeats[ip][1];

  double arr[17];
#pragma unroll
  for (int t = 0; t < 17; ++t) arr[t] = 1.0e300;

#pragma unroll 1
  for (int cc = 0; cc < 32; ++cc) {            // rolled: inner net has const idx
    const int j = q * 32 + cc;                 // wave-uniform -> LDS broadcast
    const float2 cj = *(const float2*)&sFeats[j][0];
    const float mj  = sFeats[j][7];
    const float dx = xi - cj.x, dy = yi - cj.y;
    const float d  = sqrtf(dx * dx + dy * dy);
    const float dd = (mj > 0.5f) ? d : 3.0e38f;
    double key = (double)__float_as_uint(dd) * 128.0 + (double)j;  // exact
#pragma unroll
    for (int t = 0; t < 17; ++t) {             // branchless sorted insert
      const double lo = fmin(arr[t], key);
      key    = fmax(arr[t], key);
      arr[t] = lo;
    }
  }

  // waves 4-7 publish their quarter's list (FULL unroll: const arr idx)
  if (wave >= 4) {
#pragma unroll
    for (int t = 0; t < 17; ++t) lists[(q * 17 + t) * 64 + lane] = arr[t];
  }
  __syncthreads();
  if (wave < 4) {            // stage 1: merge quarter q^1
#pragma unroll
    for (int t = 0; t < 17; ++t) {
      double key = lists[((q ^ 1) * 17 + t) * 64 + lane];
#pragma unroll
      for (int u = 0; u < 17; ++u) {
        const double lo = fmin(arr[u], key);
        key    = fmax(arr[u], key);
        arr[u] = lo;
      }
    }
  }
  __syncthreads();
  if (wave < 4) {            // publish stage-1 result {q, q^1}
#pragma unroll
    for (int t = 0; t < 17; ++t) lists[(q * 17 + t) * 64 + lane] = arr[t];
  }
  __syncthreads();
  if (wave < 4) {            // stage 2: merge {q^2, q^3}
#pragma unroll
    for (int t = 0; t < 17; ++t) {
      double key = lists[((q ^ 2) * 17 + t) * 64 + lane];
#pragma unroll
      for (int u = 0; u < 17; ++u) {
        const double lo = fmin(arr[u], key);
        key    = fmax(arr[u], key);
        arr[u] = lo;
      }
    }
  }
  // waves with q==0 hold the full top-17; write all 16 ranks (const arr idx)
  if (wave < 4 && q == 0) {
#pragma unroll
    for (int t = 1; t < 17; ++t) {
      const unsigned long long kv = (unsigned long long)arr[t];
      sIdx[lane][t - 1] = (unsigned short)(kv & 127);
    }
  }
  __syncthreads();   // sIdx ready; lists region free for sH1 buffers

  // ---- W2 B-fragments: 4 n-tiles x 8 k-steps (128 regs, read-only -> AGPR
  // friendly), after KNN so arr[17] is dead before these go live.
  // Wave owns cols [(wave&3)*64, +64) for points {2*(wave>>2), +1}.
  const int tb  = (wave & 3) * 4;    // first n-tile
  const int pg2 = wave >> 2;         // point-pair id (0/1)
  bf16x8 w2f[4][8];
  float  b2v[4];
#pragma unroll
  for (int tt = 0; tt < 4; ++tt) {
    const int n = (tb + tt) * 16 + c16;
#pragma unroll
    for (int kk = 0; kk < 8; ++kk) {
#pragma unroll
      for (int j = 0; j < 8; ++j)
        w2f[tt][kk][j] = (__bf16)W2[(kk * 32 + qd * 8 + j) * H_SZ + n];
    }
    b2v[tt] = b2[n];
  }

  // ---- Phase 1 (transposed GEMM1) for iteration it1 into buffer sH1w ----
  auto phase1 = [&](int it1, __bf16* __restrict__ sH1w) {
    const int pl = it1 * 4 + (wave >> 1);  // local point 0..63
    const int pg = ph * 64 + pl;           // global row in sFeats
    const int hh = wave & 1;               // W1-tile half
    const int nb = sIdx[pl][c16];
    const float* cf = &sFeats[pg][0];
    float4 nf0 = *(const float4*)&sFeats[nb][0];
    float4 nf1 = *(const float4*)&sFeats[nb][4];
    const float nfv[8] = {nf0.x, nf0.y, nf0.z, nf0.w, nf1.x, nf1.y, nf1.z, nf1.w};
    float ed[8];
    if (qd == 0) {        // k = 0..7: central[0..6], (neigh-central)[0]
#pragma unroll
      for (int j = 0; j < 7; ++j) ed[j] = cf[j];
      ed[7] = nfv[0] - cf[0];
    } else if (qd == 1) { // k = 8..15: (n-c)[1..6], bias-1.0 at k=14, pad
#pragma unroll
      for (int j = 0; j < 6; ++j) ed[j] = nfv[j + 1] - cf[j + 1];
      ed[6] = 1.0f; ed[7] = 0.0f;
    } else {              // k = 16..31: zero pad (lanes>=32 A-frag don't-care)
#pragma unroll
      for (int j = 0; j < 8; ++j) ed[j] = 0.0f;
    }
    bf16x8 af;
#pragma unroll
    for (int j = 0; j < 8; ++j) af[j] = (__bf16)ed[j];

#pragma unroll
    for (int t = 0; t < 8; ++t) {
      const int tt = hh * 8 + t;
      // lanes >=32: same-address broadcast read; value is don't-care (af==0)
      bf16x8 w1t = *(const bf16x8*)&sW1[tt][lane & 31][0];
      f32x4 acc = {0.0f, 0.0f, 0.0f, 0.0f};
      acc = __builtin_amdgcn_mfma_f32_16x16x32_bf16(w1t, af, acc, 0, 0, 0);
      bf16x4 hv;
#pragma unroll
      for (int rr = 0; rr < 4; ++rr) {
        float h = acc[rr];
        h = h > 0.0f ? h : 0.0f;
        hv[rr] = (__bf16)h;
      }
      // chunk-major: n = tt*16 + qd*4 + rr -> kc = tt*2 + (qd>>1), off = (qd&1)*4
      const int kc = tt * 2 + (qd >> 1);
      *(bf16x4*)&sH1w[(((size_t)(wave >> 1) * 32 + kc) * 16 + c16) * 8 + (qd & 1) * 4] = hv;
    }
  };

  // ---- Phase 2: h1(16x256) @ W2; wave does pts {2*pg2,+1} x cols [tb*16,+64) ----
  auto phase2 = [&](int it2, const __bf16* __restrict__ sH1r) {
    f32x4 acc2[2][4] = {};
#pragma unroll
    for (int kk = 0; kk < 8; ++kk) {
      bf16x8 a[2];
#pragma unroll
      for (int pi = 0; pi < 2; ++pi) {  // A[m=c16][k = kk*32+qd*8..+7] -> kc = kk*4+qd
        const int pp = pg2 * 2 + pi;
        a[pi] = *(const bf16x8*)&sH1r[(((size_t)pp * 32 + kk * 4 + qd) * 16 + c16) * 8];
      }
#pragma unroll
      for (int pi = 0; pi < 2; ++pi) {
#pragma unroll
        for (int tt = 0; tt < 4; ++tt)
          acc2[pi][tt] = __builtin_amdgcn_mfma_f32_16x16x32_bf16(a[pi], w2f[tt][kk], acc2[pi][tt], 0, 0, 0);
      }
    }

#pragma unroll
    for (int pi = 0; pi < 2; ++pi) {
      const int ptg = ph * 64 + it2 * 4 + pg2 * 2 + pi;
      const float msk  = sFeats[ptg][7];
      const float keep = (msk > 0.5f) ? 1.0f : 0.0f;
      float sarr[4];
#pragma unroll
      for (int tt = 0; tt < 4; ++tt) {
        float s = 0.0f;
#pragma unroll
        for (int rr = 0; rr < 4; ++rr) {
          float h = acc2[pi][tt][rr] + b2v[tt];
          s += (h > 0.0f ? h : 0.0f);
        }
        s += __shfl_xor(s, 16, 64);   // sum 4 quads -> full 16-row sum
        s += __shfl_xor(s, 32, 64);
        sarr[tt] = s;
      }
      // lane stores col = (wave&3)*64 + lane; select sarr[lane>>4] branchlessly
      const int ls = lane >> 4;
      const float va = (ls & 1) ? sarr[1] : sarr[0];
      const float vb = (ls & 1) ? sarr[3] : sarr[2];
      const float v  = (ls & 2) ? vb : va;
      const float agg = v * (1.0f / 16.0f);
      const float o = agg > 0.0f ? agg : 0.2f * agg;
      out[((size_t)(b * P_SZ + ptg)) * CH_OUT + (wave & 3) * 64 + lane] = keep * o;
    }
  };

  // =================  pipelined main loop: 1 barrier / iter  =================
  phase1(0, buf0);
  __syncthreads();
#pragma unroll 1
  for (int it = 0; it < 16; ++it) {
    __bf16* rd = (it & 1) ? buf1 : buf0;
    __bf16* wr = (it & 1) ? buf0 : buf1;
    if (it < 15) phase1(it + 1, wr);   // produce next tile into other buffer
    phase2(it, rd);                    // consume current tile
    __syncthreads();                   // wr complete before next iter reads it
  }
}

// ---------------------------------------------------------------------------
extern "C" void kernel_launch(void* const* d_in, const int* in_sizes, int n_in,
                              void* d_out, int out_size, void* d_ws, size_t ws_size,
                              hipStream_t stream) {
  const float* ev = (const float*)d_in[0];
  const float* W1 = (const float*)d_in[1];
  const float* b1 = (const float*)d_in[2];
  const float* W2 = (const float*)d_in[3];
  const float* b2 = (const float*)d_in[4];
  float* out = (float*)d_out;

  edgeconv_fused<<<B_SZ * 2, 512, 0, stream>>>(ev, W1, b1, W2, b2, out);
}

// Round 3
// 165.318 us; speedup vs baseline: 1.3690x; 1.3690x over previous
//
#include <hip/hip_runtime.h>

#define B_SZ 256
#define P_SZ 128
#define F_SZ 7
#define H_SZ 256
#define KNB  16
#define CH_OUT 264   // H + F + 1

typedef __bf16 bf16x8 __attribute__((ext_vector_type(8)));
typedef __bf16 bf16x4 __attribute__((ext_vector_type(4)));
typedef float  f32x4  __attribute__((ext_vector_type(4)));

// ---------------------------------------------------------------------------
// Grid = 512: block (b, ph) handles batch b, points ph*64..+63. 8 waves.
// Geometry: launch_bounds(512,4) -> 2 blocks/CU (round-2 showed 1 block/CU
// kills overlap: 22% occupancy, +45 us). LDS = 78 KB.
// THIS ROUND (VALU cuts, output bit-identical):
//  * KNN rewritten: 8-way candidate split (16 cands/wave, no duplicated
//    scans), self excluded in scan mask (16-deep lists), tiered insertion
//    (depth 8 then 16 = 192 pairs), and Batcher half-cleaner + 4-stage
//    bitonic merge (80 f64 ops vs 578 for the old 17x17 insert-merge).
//    3-stage merge tree. Exact same f64 keys -> identical sorted top-16.
//  * Phase 2 split into two 2-point groups (acc2 16 regs not 32), phase1
//    sandwiched between -> peak liveness under the 128-reg cap.
// CRITICAL: every loop indexing per-lane arrays (arr/oth/w2f/acc2) must be
// FULLY UNROLLED (constant indices) or the compiler demotes to scratch.
//  Main loop software-pipelined: sH1 double-buffered (2 x 32 KB), ONE barrier
//    per iteration: phase1(it+1)->buf[!cur] overlaps phase2(it)<-buf[cur].
//  sW1 compressed to [16][32][8] (8 KB): rows 32..63 structural zeros; lanes
//    >=32 read sW1[tt][lane&31] (same-address broadcast, af==0 there).
//  sH1 chunk-major [pt][kc=k/8][m=16][8el]: phase-2 b128 reads conflict-free,
//  phase-1 b64 stores 2-way (free).
// ---------------------------------------------------------------------------
__global__ __launch_bounds__(512, 4) void edgeconv_fused(
    const float* __restrict__ ev, const float* __restrict__ W1,
    const float* __restrict__ b1, const float* __restrict__ W2,
    const float* __restrict__ b2, float* __restrict__ out) {
  const int b    = blockIdx.x >> 1;
  const int ph   = blockIdx.x & 1;
  const int tid  = threadIdx.x;
  const int lane = tid & 63;
  const int wave = tid >> 6;         // 0..7
  const int qd   = lane >> 4;        // 0..3
  const int c16  = lane & 15;

  __shared__ float sFeats[P_SZ][8];                     // 4 KB (full batch)
  __shared__ __align__(16) __bf16 sW1[16][32][8];       // 8 KB, k<16 half only
  __shared__ unsigned short sIdx[64][KNB];              // 2 KB (this block's pts)
  // union: 2 x sH1 double buffer (2 x 32768 B); KNN lists [8][16][64] f64
  // = 65536 B overlay exactly (disjoint lifetimes, barrier-separated).
  __shared__ __align__(16) unsigned char sU[2 * 32768];
  double* lists = (double*)sU;                          // [eighth][16][64]
  __bf16* buf0  = (__bf16*)sU;                          // sH1 buffer 0
  __bf16* buf1  = (__bf16*)(sU + 32768);                // sH1 buffer 1

  // ---- stage events + W1 frags (bias folded in at k=14; k<16 half only) ----
  if (tid < 2 * P_SZ)
    ((float4*)&sFeats[0][0])[tid] = ((const float4*)(ev + (size_t)b * P_SZ * 8))[tid];
  if (tid < 512) {   // 16 tiles x 32 rows
    const int t = tid >> 5, l32 = tid & 31;
    const int qq = l32 >> 4, cc = l32 & 15;
    const int n = t * 16 + cc;
    bf16x8 v;
#pragma unroll
    for (int j = 0; j < 8; ++j) {
      const int k = qq * 8 + j;
      float w = 0.0f;
      if (k < 2 * F_SZ) w = W1[k * H_SZ + n];
      else if (k == 2 * F_SZ) w = b1[n];   // bias row, edge supplies 1.0
      v[j] = (__bf16)w;
    }
    *(bf16x8*)&sW1[t][l32][0] = v;
  }
  __syncthreads();

  // ---- feats passthrough + mask channel (needs only sFeats) ----
  {
    const int pl = tid >> 3, ch = tid & 7;       // 64 pts x 8 ch
    const int pg = ph * 64 + pl;
    const float msk = sFeats[pg][7];
    float v;
    if (ch < 7) {
      float fv = sFeats[pg][ch];
      fv = fv > 0.0f ? fv : 0.2f * fv;
      v = (msk > 0.5f ? 1.0f : 0.0f) * fv;
    } else {
      v = msk;
    }
    out[((size_t)(b * P_SZ + pg)) * CH_OUT + H_SZ + ch] = v;
  }

  // ===================  KNN (f64 keys, bitonic merge tree)  =================
  // lane-point = ph*64 + lane; wave scans candidates wave*16..+15 (eighth).
  const int ip = ph * 64 + lane;
  const float xi = sFeats[ip][0], yi = sFeats[ip][1];

  double arr[16];
#pragma unroll
  for (int t = 0; t < 16; ++t) arr[t] = 1.0e300;

  // tiered sorted-insert scan: depth 8 for first 8 cands, depth 16 after.
#pragma unroll 1
  for (int cc = 0; cc < 8; ++cc) {
    const int j = wave * 16 + cc;              // wave-uniform -> LDS broadcast
    const float2 cj = *(const float2*)&sFeats[j][0];
    const float mj  = sFeats[j][7];
    const float dx = xi - cj.x, dy = yi - cj.y;
    const float d  = sqrtf(dx * dx + dy * dy);
    const float dd = (mj > 0.5f && j != ip) ? d : 3.0e38f;  // self excluded
    double key = (double)__float_as_uint(dd) * 128.0 + (double)j;  // exact
#pragma unroll
    for (int t = 0; t < 8; ++t) {
      const double lo = fmin(arr[t], key);
      key    = fmax(arr[t], key);
      arr[t] = lo;
    }
  }
#pragma unroll 1
  for (int cc = 8; cc < 16; ++cc) {
    const int j = wave * 16 + cc;
    const float2 cj = *(const float2*)&sFeats[j][0];
    const float mj  = sFeats[j][7];
    const float dx = xi - cj.x, dy = yi - cj.y;
    const float d  = sqrtf(dx * dx + dy * dy);
    const float dd = (mj > 0.5f && j != ip) ? d : 3.0e38f;
    double key = (double)__float_as_uint(dd) * 128.0 + (double)j;
#pragma unroll
    for (int t = 0; t < 16; ++t) {
      const double lo = fmin(arr[t], key);
      key    = fmax(arr[t], key);
      arr[t] = lo;
    }
  }

  // merge: half-cleaner (16 fmin) + 4-stage bitonic sort of bitonic seq.
  auto mergeList = [&](const double* src) {
    double oth[16];
#pragma unroll
    for (int t = 0; t < 16; ++t) oth[t] = src[t * 64 + lane];
#pragma unroll
    for (int t = 0; t < 16; ++t) arr[t] = fmin(arr[t], oth[15 - t]);
#pragma unroll
    for (int d = 8; d >= 1; d >>= 1) {
#pragma unroll
      for (int i = 0; i < 16; ++i) {
        if ((i & d) == 0) {
          const double lo = fmin(arr[i], arr[i + d]);
          arr[i + d] = fmax(arr[i], arr[i + d]);
          arr[i] = lo;
        }
      }
    }
  };
  auto publish = [&](int slot) {
#pragma unroll
    for (int t = 0; t < 16; ++t) lists[(slot * 16 + t) * 64 + lane] = arr[t];
  };

  if (wave >= 4) publish(wave);          // scan lists of eighths 4..7
  __syncthreads();
  if (wave < 4) {                        // stage A: {e, e+4}
    mergeList(&lists[((wave + 4) * 16) * 64]);
    publish(wave);
  }
  __syncthreads();
  if (wave == 0 || wave == 2) {          // stage B: {0,1,4,5} / {2,3,6,7}
    mergeList(&lists[((wave ^ 1) * 16) * 64]);
    if (wave == 2) publish(2);
  }
  __syncthreads();
  if (wave == 0) {                       // stage C: full top-16, sorted asc
    mergeList(&lists[(2 * 16) * 64]);
#pragma unroll
    for (int t = 0; t < 16; ++t) {
      const unsigned long long kv = (unsigned long long)arr[t];
      sIdx[lane][t] = (unsigned short)(kv & 127);
    }
  }
  __syncthreads();   // sIdx ready; lists region free for sH1 buffers

  // ---- W2 B-fragments: 2 n-tiles x 8 k-steps (64 regs), after KNN so
  // arr/oth are dead before these go live (stay under the 128-reg cap).
  const int t0 = wave * 2;
  bf16x8 w2f[2][8];
  float  b2v[2];
#pragma unroll
  for (int tt = 0; tt < 2; ++tt) {
    const int n = (t0 + tt) * 16 + c16;
#pragma unroll
    for (int kk = 0; kk < 8; ++kk) {
#pragma unroll
      for (int j = 0; j < 8; ++j)
        w2f[tt][kk][j] = (__bf16)W2[(kk * 32 + qd * 8 + j) * H_SZ + n];
    }
    b2v[tt] = b2[n];
  }

  // ---- Phase 1 (transposed GEMM1) for iteration it1 into buffer sH1w ----
  auto phase1 = [&](int it1, __bf16* __restrict__ sH1w) {
    const int pl = it1 * 4 + (wave >> 1);  // local point 0..63
    const int pg = ph * 64 + pl;           // global row in sFeats
    const int hh = wave & 1;               // W1-tile half
    const int nb = sIdx[pl][c16];
    const float* cf = &sFeats[pg][0];
    float4 nf0 = *(const float4*)&sFeats[nb][0];
    float4 nf1 = *(const float4*)&sFeats[nb][4];
    const float nfv[8] = {nf0.x, nf0.y, nf0.z, nf0.w, nf1.x, nf1.y, nf1.z, nf1.w};
    float ed[8];
    if (qd == 0) {        // k = 0..7: central[0..6], (neigh-central)[0]
#pragma unroll
      for (int j = 0; j < 7; ++j) ed[j] = cf[j];
      ed[7] = nfv[0] - cf[0];
    } else if (qd == 1) { // k = 8..15: (n-c)[1..6], bias-1.0 at k=14, pad
#pragma unroll
      for (int j = 0; j < 6; ++j) ed[j] = nfv[j + 1] - cf[j + 1];
      ed[6] = 1.0f; ed[7] = 0.0f;
    } else {              // k = 16..31: zero pad (lanes>=32 A-frag don't-care)
#pragma unroll
      for (int j = 0; j < 8; ++j) ed[j] = 0.0f;
    }
    bf16x8 af;
#pragma unroll
    for (int j = 0; j < 8; ++j) af[j] = (__bf16)ed[j];

#pragma unroll
    for (int t = 0; t < 8; ++t) {
      const int tt = hh * 8 + t;
      // lanes >=32: same-address broadcast read; value is don't-care (af==0)
      bf16x8 w1t = *(const bf16x8*)&sW1[tt][lane & 31][0];
      f32x4 acc = {0.0f, 0.0f, 0.0f, 0.0f};
      acc = __builtin_amdgcn_mfma_f32_16x16x32_bf16(w1t, af, acc, 0, 0, 0);
      bf16x4 hv;
#pragma unroll
      for (int rr = 0; rr < 4; ++rr) {
        float h = acc[rr];
        h = h > 0.0f ? h : 0.0f;
        hv[rr] = (__bf16)h;
      }
      // chunk-major: n = tt*16 + qd*4 + rr -> kc = tt*2 + (qd>>1), off = (qd&1)*4
      const int kc = tt * 2 + (qd >> 1);
      *(bf16x4*)&sH1w[(((size_t)(wave >> 1) * 32 + kc) * 16 + c16) * 8 + (qd & 1) * 4] = hv;
    }
  };

  // ---- Phase 2 group g (points g*2, g*2+1): acc2 = 16 regs live ----
  auto phase2group = [&](int it2, const __bf16* __restrict__ sH1r, int g) {
    f32x4 acc2[2][2] = {};
#pragma unroll
    for (int kk = 0; kk < 8; ++kk) {
      bf16x8 a[2];
#pragma unroll
      for (int pi = 0; pi < 2; ++pi) {  // A[m=c16][k = kk*32+qd*8..+7] -> kc = kk*4+qd
        const int pp = g * 2 + pi;
        a[pi] = *(const bf16x8*)&sH1r[(((size_t)pp * 32 + kk * 4 + qd) * 16 + c16) * 8];
      }
#pragma unroll
      for (int pi = 0; pi < 2; ++pi) {
        acc2[pi][0] = __builtin_amdgcn_mfma_f32_16x16x32_bf16(a[pi], w2f[0][kk], acc2[pi][0], 0, 0, 0);
        acc2[pi][1] = __builtin_amdgcn_mfma_f32_16x16x32_bf16(a[pi], w2f[1][kk], acc2[pi][1], 0, 0, 0);
      }
    }

#pragma unroll
    for (int pi = 0; pi < 2; ++pi) {
      const int ptg = ph * 64 + it2 * 4 + g * 2 + pi;
      const float msk  = sFeats[ptg][7];
      const float keep = (msk > 0.5f) ? 1.0f : 0.0f;
      float sarr[2];
#pragma unroll
      for (int tt = 0; tt < 2; ++tt) {
        float s = 0.0f;
#pragma unroll
        for (int rr = 0; rr < 4; ++rr) {
          float h = acc2[pi][tt][rr] + b2v[tt];
          s += (h > 0.0f ? h : 0.0f);
        }
        s += __shfl_xor(s, 16, 64);   // sum 4 quads -> full 16-row sum
        s += __shfl_xor(s, 32, 64);
        sarr[tt] = s;
      }
      if (lane < 32) {                // half-wave contiguous 128 B store
        const float v = (lane >> 4) ? sarr[1] : sarr[0];
        const float agg = v * (1.0f / 16.0f);
        const float o = agg > 0.0f ? agg : 0.2f * agg;
        out[((size_t)(b * P_SZ + ptg)) * CH_OUT + t0 * 16 + lane] = keep * o;
      }
    }
  };

  // =================  pipelined main loop: 1 barrier / iter  =================
  phase1(0, buf0);
  __syncthreads();
#pragma unroll 1
  for (int it = 0; it < 16; ++it) {
    const __bf16* rd = (it & 1) ? buf1 : buf0;
    __bf16* wr = (it & 1) ? buf0 : buf1;
    phase2group(it, rd, 0);            // MFMA-heavy, 16 acc regs
    if (it < 15) phase1(it + 1, wr);   // VALU-heavy, fills other buffer
    phase2group(it, rd, 1);
    __syncthreads();                   // wr complete before next iter reads it
  }
}

// ---------------------------------------------------------------------------
extern "C" void kernel_launch(void* const* d_in, const int* in_sizes, int n_in,
                              void* d_out, int out_size, void* d_ws, size_t ws_size,
                              hipStream_t stream) {
  const float* ev = (const float*)d_in[0];
  const float* W1 = (const float*)d_in[1];
  const float* b1 = (const float*)d_in[2];
  const float* W2 = (const float*)d_in[3];
  const float* b2 = (const float*)d_in[4];
  float* out = (float*)d_out;

  edgeconv_fused<<<B_SZ * 2, 512, 0, stream>>>(ev, W1, b1, W2, b2, out);
}

// Round 4
// 162.411 us; speedup vs baseline: 1.3935x; 1.0179x over previous
//
#include <hip/hip_runtime.h>

#define B_SZ 256
#define P_SZ 128
#define F_SZ 7
#define H_SZ 256
#define KNB  16
#define CH_OUT 264   // H + F + 1

typedef __bf16 bf16x8 __attribute__((ext_vector_type(8)));
typedef __bf16 bf16x4 __attribute__((ext_vector_type(4)));
typedef float  f32x4  __attribute__((ext_vector_type(4)));
typedef float  f32x16 __attribute__((ext_vector_type(16)));

// ---------------------------------------------------------------------------
// Grid = 512: block (b, ph) handles batch b, points ph*64..+63. 8 waves.
// Geometry: launch_bounds(512,4) -> 2 blocks/CU. LDS = 78 KB.
// THIS ROUND: GEMM2 moved to mfma_f32_32x32x16_bf16 (4060 vs 3377 FLOP/cyc,
//   m119): m=32 = 2 points x 16 neighbors stacked, n=32 = the wave's col
//   slice, 16 k-steps. Halves MFMA instruction count (4096 vs 8192 / block),
//   keeps w2f at 64 VGPRs, same LDS bytes, and shrinks the epilogue to one
//   shfl_xor(32) per point (C rows: ptA in regs 0-7, ptB in regs 8-15).
// Pipe budget at round-3 (117 us): LDS ~43%, MFMA ~32%, VALU ~16% -> this
//   attacks MFMA pipe time + issue slots + epilogue VALU.
// CRITICAL: every loop indexing per-lane arrays must be FULLY UNROLLED
//   (constant indices) or the compiler demotes to scratch.
//  KNN: 8-way split scan (16 cands/wave), tiered insert (8 then 16), Batcher
//    half-cleaner + bitonic merges, exact f64 keys -> exact top-16.
//  Main loop software-pipelined: sH1 double-buffered (2 x 32 KB), ONE barrier
//    per iteration: phase1(it+1)->buf[!cur] sandwiched between the two
//    phase-2 groups of iteration it.
//  sW1 compressed to [16][32][8] (8 KB): rows 32..63 structural zeros; lanes
//    >=32 read sW1[tt][lane&31] (same-address broadcast, af==0 there).
//  sH1 chunk-major [pt][kc=k/8][nbr=16][8el]: phase-2 b128 reads conflict-
//    free (8 lanes/phase span all 32 banks), phase-1 b64 stores 2-way (free).
// ---------------------------------------------------------------------------
__global__ __launch_bounds__(512, 4) void edgeconv_fused(
    const float* __restrict__ ev, const float* __restrict__ W1,
    const float* __restrict__ b1, const float* __restrict__ W2,
    const float* __restrict__ b2, float* __restrict__ out) {
  const int b    = blockIdx.x >> 1;
  const int ph   = blockIdx.x & 1;
  const int tid  = threadIdx.x;
  const int lane = tid & 63;
  const int wave = tid >> 6;         // 0..7
  const int qd   = lane >> 4;        // 0..3
  const int c16  = lane & 15;

  __shared__ float sFeats[P_SZ][8];                     // 4 KB (full batch)
  __shared__ __align__(16) __bf16 sW1[16][32][8];       // 8 KB, k<16 half only
  __shared__ unsigned short sIdx[64][KNB];              // 2 KB (this block's pts)
  // union: 2 x sH1 double buffer (2 x 32768 B); KNN lists [8][16][64] f64
  // = 65536 B overlay exactly (disjoint lifetimes, barrier-separated).
  __shared__ __align__(16) unsigned char sU[2 * 32768];
  double* lists = (double*)sU;                          // [eighth][16][64]
  __bf16* buf0  = (__bf16*)sU;                          // sH1 buffer 0
  __bf16* buf1  = (__bf16*)(sU + 32768);                // sH1 buffer 1

  // ---- stage events + W1 frags (bias folded in at k=14; k<16 half only) ----
  if (tid < 2 * P_SZ)
    ((float4*)&sFeats[0][0])[tid] = ((const float4*)(ev + (size_t)b * P_SZ * 8))[tid];
  if (tid < 512) {   // 16 tiles x 32 rows
    const int t = tid >> 5, l32 = tid & 31;
    const int qq = l32 >> 4, cc = l32 & 15;
    const int n = t * 16 + cc;
    bf16x8 v;
#pragma unroll
    for (int j = 0; j < 8; ++j) {
      const int k = qq * 8 + j;
      float w = 0.0f;
      if (k < 2 * F_SZ) w = W1[k * H_SZ + n];
      else if (k == 2 * F_SZ) w = b1[n];   // bias row, edge supplies 1.0
      v[j] = (__bf16)w;
    }
    *(bf16x8*)&sW1[t][l32][0] = v;
  }
  __syncthreads();

  // ---- feats passthrough + mask channel (needs only sFeats) ----
  {
    const int pl = tid >> 3, ch = tid & 7;       // 64 pts x 8 ch
    const int pg = ph * 64 + pl;
    const float msk = sFeats[pg][7];
    float v;
    if (ch < 7) {
      float fv = sFeats[pg][ch];
      fv = fv > 0.0f ? fv : 0.2f * fv;
      v = (msk > 0.5f ? 1.0f : 0.0f) * fv;
    } else {
      v = msk;
    }
    out[((size_t)(b * P_SZ + pg)) * CH_OUT + H_SZ + ch] = v;
  }

  // ===================  KNN (f64 keys, bitonic merge tree)  =================
  // lane-point = ph*64 + lane; wave scans candidates wave*16..+15 (eighth).
  const int ip = ph * 64 + lane;
  const float xi = sFeats[ip][0], yi = sFeats[ip][1];

  double arr[16];
#pragma unroll
  for (int t = 0; t < 16; ++t) arr[t] = 1.0e300;

  // tiered sorted-insert scan: depth 8 for first 8 cands, depth 16 after.
#pragma unroll 1
  for (int cc = 0; cc < 8; ++cc) {
    const int j = wave * 16 + cc;              // wave-uniform -> LDS broadcast
    const float2 cj = *(const float2*)&sFeats[j][0];
    const float mj  = sFeats[j][7];
    const float dx = xi - cj.x, dy = yi - cj.y;
    const float d  = sqrtf(dx * dx + dy * dy);
    const float dd = (mj > 0.5f && j != ip) ? d : 3.0e38f;  // self excluded
    double key = (double)__float_as_uint(dd) * 128.0 + (double)j;  // exact
#pragma unroll
    for (int t = 0; t < 8; ++t) {
      const double lo = fmin(arr[t], key);
      key    = fmax(arr[t], key);
      arr[t] = lo;
    }
  }
#pragma unroll 1
  for (int cc = 8; cc < 16; ++cc) {
    const int j = wave * 16 + cc;
    const float2 cj = *(const float2*)&sFeats[j][0];
    const float mj  = sFeats[j][7];
    const float dx = xi - cj.x, dy = yi - cj.y;
    const float d  = sqrtf(dx * dx + dy * dy);
    const float dd = (mj > 0.5f && j != ip) ? d : 3.0e38f;
    double key = (double)__float_as_uint(dd) * 128.0 + (double)j;
#pragma unroll
    for (int t = 0; t < 16; ++t) {
      const double lo = fmin(arr[t], key);
      key    = fmax(arr[t], key);
      arr[t] = lo;
    }
  }

  // merge: half-cleaner (16 fmin) + 4-stage bitonic sort of bitonic seq.
  auto mergeList = [&](const double* src) {
    double oth[16];
#pragma unroll
    for (int t = 0; t < 16; ++t) oth[t] = src[t * 64 + lane];
#pragma unroll
    for (int t = 0; t < 16; ++t) arr[t] = fmin(arr[t], oth[15 - t]);
#pragma unroll
    for (int d = 8; d >= 1; d >>= 1) {
#pragma unroll
      for (int i = 0; i < 16; ++i) {
        if ((i & d) == 0) {
          const double lo = fmin(arr[i], arr[i + d]);
          arr[i + d] = fmax(arr[i], arr[i + d]);
          arr[i] = lo;
        }
      }
    }
  };
  auto publish = [&](int slot) {
#pragma unroll
    for (int t = 0; t < 16; ++t) lists[(slot * 16 + t) * 64 + lane] = arr[t];
  };

  if (wave >= 4) publish(wave);          // scan lists of eighths 4..7
  __syncthreads();
  if (wave < 4) {                        // stage A: {e, e+4}
    mergeList(&lists[((wave + 4) * 16) * 64]);
    publish(wave);
  }
  __syncthreads();
  if (wave == 0 || wave == 2) {          // stage B: {0,1,4,5} / {2,3,6,7}
    mergeList(&lists[((wave ^ 1) * 16) * 64]);
    if (wave == 2) publish(2);
  }
  __syncthreads();
  if (wave == 0) {                       // stage C: full top-16, sorted asc
    mergeList(&lists[(2 * 16) * 64]);
#pragma unroll
    for (int t = 0; t < 16; ++t) {
      const unsigned long long kv = (unsigned long long)arr[t];
      sIdx[lane][t] = (unsigned short)(kv & 127);
    }
  }
  __syncthreads();   // sIdx ready; lists region free for sH1 buffers

  // ---- W2 B-fragments for 32x32x16: wave owns cols [wave*32, +32).
  // Per lane: col = wave*32 + (lane&31), k = kk*16 + (lane>>5)*8 + j.
  // 16 frags x 4 VGPR = 64 regs; loaded after KNN (arr/oth dead).
  const int wcol  = wave * 32 + (lane & 31);
  const int khalf = (lane >> 5) * 8;
  bf16x8 w2f[16];
#pragma unroll
  for (int kk = 0; kk < 16; ++kk) {
#pragma unroll
    for (int j = 0; j < 8; ++j)
      w2f[kk][j] = (__bf16)W2[(kk * 16 + khalf + j) * H_SZ + wcol];
  }
  const float b2v = b2[wcol];

  // ---- Phase 1 (transposed GEMM1) for iteration it1 into buffer sH1w ----
  auto phase1 = [&](int it1, __bf16* __restrict__ sH1w) {
    const int pl = it1 * 4 + (wave >> 1);  // local point 0..63
    const int pg = ph * 64 + pl;           // global row in sFeats
    const int hh = wave & 1;               // W1-tile half
    const int nb = sIdx[pl][c16];
    const float* cf = &sFeats[pg][0];
    float4 nf0 = *(const float4*)&sFeats[nb][0];
    float4 nf1 = *(const float4*)&sFeats[nb][4];
    const float nfv[8] = {nf0.x, nf0.y, nf0.z, nf0.w, nf1.x, nf1.y, nf1.z, nf1.w};
    float ed[8];
    if (qd == 0) {        // k = 0..7: central[0..6], (neigh-central)[0]
#pragma unroll
      for (int j = 0; j < 7; ++j) ed[j] = cf[j];
      ed[7] = nfv[0] - cf[0];
    } else if (qd == 1) { // k = 8..15: (n-c)[1..6], bias-1.0 at k=14, pad
#pragma unroll
      for (int j = 0; j < 6; ++j) ed[j] = nfv[j + 1] - cf[j + 1];
      ed[6] = 1.0f; ed[7] = 0.0f;
    } else {              // k = 16..31: zero pad (lanes>=32 A-frag don't-care)
#pragma unroll
      for (int j = 0; j < 8; ++j) ed[j] = 0.0f;
    }
    bf16x8 af;
#pragma unroll
    for (int j = 0; j < 8; ++j) af[j] = (__bf16)ed[j];

#pragma unroll
    for (int t = 0; t < 8; ++t) {
      const int tt = hh * 8 + t;
      // lanes >=32: same-address broadcast read; value is don't-care (af==0)
      bf16x8 w1t = *(const bf16x8*)&sW1[tt][lane & 31][0];
      f32x4 acc = {0.0f, 0.0f, 0.0f, 0.0f};
      acc = __builtin_amdgcn_mfma_f32_16x16x32_bf16(w1t, af, acc, 0, 0, 0);
      bf16x4 hv;
#pragma unroll
      for (int rr = 0; rr < 4; ++rr) {
        float h = acc[rr];
        h = h > 0.0f ? h : 0.0f;
        hv[rr] = (__bf16)h;
      }
      // chunk-major: n = tt*16 + qd*4 + rr -> kc = tt*2 + (qd>>1), off = (qd&1)*4
      const int kc = tt * 2 + (qd >> 1);
      *(bf16x4*)&sH1w[(((size_t)(wave >> 1) * 32 + kc) * 16 + c16) * 8 + (qd & 1) * 4] = hv;
    }
  };

  // ---- Phase 2 group g (points {g*2, g*2+1} stacked into m=32) ----
  // A-frag: m = lane&31 (pt=(lane>>4)&1, nbr=lane&15), k-chunk kc=kk*2+(lane>>5).
  // C/D: col = lane&31, row = (reg&3)+8*(reg>>2)+4*(lane>>5):
  //   ptA rows 0..15 live in regs 0..7 (split across lane halves),
  //   ptB rows 16..31 in regs 8..15 -> one shfl_xor(32) per point-sum.
  auto phase2group = [&](int it2, const __bf16* __restrict__ sH1r, int g) {
    f32x16 acc = {};
    const int app = g * 2 + ((lane >> 4) & 1);
    const int anb = lane & 15;
    const int kho = lane >> 5;
#pragma unroll
    for (int kk = 0; kk < 16; ++kk) {
      const int kc = kk * 2 + kho;
      bf16x8 a = *(const bf16x8*)&sH1r[(((size_t)app * 32 + kc) * 16 + anb) * 8];
      acc = __builtin_amdgcn_mfma_f32_32x32x16_bf16(a, w2f[kk], acc, 0, 0, 0);
    }

    float sA = 0.0f, sB = 0.0f;
#pragma unroll
    for (int r = 0; r < 8; ++r) {
      const float h = acc[r] + b2v;
      sA += (h > 0.0f ? h : 0.0f);
    }
#pragma unroll
    for (int r = 8; r < 16; ++r) {
      const float h = acc[r] + b2v;
      sB += (h > 0.0f ? h : 0.0f);
    }
    sA += __shfl_xor(sA, 32, 64);       // combine the two lane-half row sets
    sB += __shfl_xor(sB, 32, 64);
    const int pi  = lane >> 5;          // lanes<32 store ptA, lanes>=32 ptB
    const float s = pi ? sB : sA;
    const int ptg = ph * 64 + it2 * 4 + g * 2 + pi;
    const float msk  = sFeats[ptg][7];
    const float keep = (msk > 0.5f) ? 1.0f : 0.0f;
    const float agg = s * (1.0f / 16.0f);
    const float o = agg > 0.0f ? agg : 0.2f * agg;
    out[((size_t)(b * P_SZ + ptg)) * CH_OUT + wave * 32 + (lane & 31)] = keep * o;
  };

  // =================  pipelined main loop: 1 barrier / iter  =================
  phase1(0, buf0);
  __syncthreads();
#pragma unroll 1
  for (int it = 0; it < 16; ++it) {
    const __bf16* rd = (it & 1) ? buf1 : buf0;
    __bf16* wr = (it & 1) ? buf0 : buf1;
    phase2group(it, rd, 0);            // MFMA-heavy, 16 acc regs
    if (it < 15) phase1(it + 1, wr);   // VALU-heavy, fills other buffer
    phase2group(it, rd, 1);
    __syncthreads();                   // wr complete before next iter reads it
  }
}

// ---------------------------------------------------------------------------
extern "C" void kernel_launch(void* const* d_in, const int* in_sizes, int n_in,
                              void* d_out, int out_size, void* d_ws, size_t ws_size,
                              hipStream_t stream) {
  const float* ev = (const float*)d_in[0];
  const float* W1 = (const float*)d_in[1];
  const float* b1 = (const float*)d_in[2];
  const float* W2 = (const float*)d_in[3];
  const float* b2 = (const float*)d_in[4];
  float* out = (float*)d_out;

  edgeconv_fused<<<B_SZ * 2, 512, 0, stream>>>(ev, W1, b1, W2, b2, out);
}